// Round 8
// baseline (639.384 us; speedup 1.0000x reference)
//
#include <hip/hip_runtime.h>

#define N_NODES 100000
#define N_EDGES 400000
#define N_GRAPHS 2048
#define HID 128
#define NLAYER 4
#define TOUT 5
#define EPSV 1e-5f
#define SLOPE 0.2f
#define MAXDEG 32

typedef float v4f __attribute__((ext_vector_type(4)));
typedef __bf16 v8bf __attribute__((ext_vector_type(8)));

static __device__ __forceinline__ unsigned short f2bf_bits(float f){
  unsigned u = __builtin_bit_cast(unsigned, f);
  unsigned r = u + 0x7fffu + ((u >> 16) & 1u);
  return (unsigned short)(r >> 16);
}
static __device__ __forceinline__ float bfbits2f(unsigned short s){
  unsigned u = ((unsigned)s) << 16;
  return __builtin_bit_cast(float, u);
}
static __device__ __forceinline__ float bflo(unsigned u){
  return __builtin_bit_cast(float, u << 16);
}
static __device__ __forceinline__ float bfhi(unsigned u){
  return __builtin_bit_cast(float, u & 0xffff0000u);
}
static __device__ __forceinline__ float lrelu(float v){
  return v>0.f ? v : SLOPE*v;
}

// h = x @ node_w + node_b  -> fp32 hbuf + packed bf16 h16
__global__ void k_hinit(const float* __restrict__ x, const float* __restrict__ nw,
                        const float* __restrict__ nb, float* __restrict__ hbuf,
                        unsigned* __restrict__ h16){
  int t = threadIdx.x;
  int node = blockIdx.x*2 + (t>>7);
  int c = t&127;
  float acc = nb[c];
  #pragma unroll
  for(int f=0; f<7; ++f) acc += x[node*7+f]*nw[f*HID+c];
  hbuf[(size_t)node*HID+c] = acc;
  float o = __shfl_xor(acc,1);
  if((c&1)==0){
    unsigned p = (unsigned)f2bf_bits(acc) | ((unsigned)f2bf_bits(o)<<16);
    h16[((size_t)node*HID+c)>>1] = p;
  }
}

// prep Me[3][16]+be[16]  AND folded BN (A,S)
__global__ void k_prep(const float* __restrict__ gat_edge_w, const float* __restrict__ att_edge,
                       const float* __restrict__ edge_w, const float* __restrict__ edge_b,
                       const float* __restrict__ gat_bias, const float* __restrict__ gamma,
                       const float* __restrict__ beta, const float* __restrict__ mean,
                       const float* __restrict__ var,
                       float* __restrict__ mebuf, float* __restrict__ bnA, float* __restrict__ bnS){
  __shared__ float Ve[128*16];
  int t = threadIdx.x;
  for(int i=t; i<NLAYER*HID; i+=256){
    float A = gamma[i]*rsqrtf(var[i]+EPSV);
    bnA[i] = A;
    bnS[i] = (gat_bias[i]-mean[i])*A + beta[i];
  }
  for(int id=t; id<2048; id+=256){
    int k = id>>4, li = id&15, l = li>>2, hh = li&3;
    const float* gw = gat_edge_w + l*16384 + k*128 + hh*32;
    const float* at = att_edge + l*128 + hh*32;
    float s = 0.f;
    #pragma unroll
    for(int c=0;c<32;++c) s += gw[c]*at[c];
    Ve[k*16+li] = s;
  }
  __syncthreads();
  if(t < 48){
    int f = t>>4, li = t&15;
    float s=0.f;
    for(int k=0;k<128;++k) s += edge_w[f*128+k]*Ve[k*16+li];
    mebuf[f*16+li] = s;
  } else if (t < 64){
    int li = t-48; float s=0.f;
    for(int k=0;k<128;++k) s += edge_b[k]*Ve[k*16+li];
    mebuf[48+li] = s;
  }
}

// swizzle gat_lin_w into MFMA B-fragment order, split into bf16 hi/lo
__global__ void k_wswz(const float* __restrict__ W, unsigned short* __restrict__ whi,
                       unsigned short* __restrict__ wlo){
  int idx = blockIdx.x*256 + threadIdx.x; // l*16384 + k*128 + c
  int l = idx>>14, k = (idx>>7)&127, c = idx&127;
  float w = W[idx];
  unsigned short hi = f2bf_bits(w);
  unsigned short lo = f2bf_bits(w - bfbits2f(hi));
  int kb=k>>5, quad=(k>>3)&3, j=k&7, cg=c>>4, r=c&15, lane=quad*16+r;
  int dst = ((l*4+kb)*8+cg)*512 + lane*8 + j;
  whi[dst]=hi; wlo[dst]=lo;
}

__global__ void k_deg(const int* __restrict__ ei, int* __restrict__ deg){
  int e = blockIdx.x*256 + threadIdx.x;
  if(e >= N_EDGES) return;
  atomicAdd(&deg[ei[N_EDGES+e]], 1);
}

// exclusive scan of deg -> rowptr (3 phases, chunk=1024)
__global__ void k_scan1(const int* __restrict__ deg, int* __restrict__ part){
  __shared__ int s[256];
  int t=threadIdx.x; int base = blockIdx.x*1024 + t*4;
  int sum=0;
  #pragma unroll
  for(int j=0;j<4;++j){ int i=base+j; sum += (i<N_NODES)? deg[i]:0; }
  s[t]=sum; __syncthreads();
  for(int off=128; off>0; off>>=1){ if(t<off) s[t]+=s[t+off]; __syncthreads(); }
  if(t==0) part[blockIdx.x]=s[0];
}
__global__ void k_scan2(int* __restrict__ part, int* __restrict__ rowptr, int nb){
  if(threadIdx.x==0 && blockIdx.x==0){
    int run=0;
    for(int i=0;i<nb;++i){ int v=part[i]; part[i]=run; run+=v; }
    rowptr[N_NODES]=run;
  }
}
__global__ void k_scan3(const int* __restrict__ deg, const int* __restrict__ part, int* __restrict__ rowptr){
  __shared__ int s[256];
  int t=threadIdx.x; int base = blockIdx.x*1024 + t*4;
  int v[4]; int sum=0; int pre[4];
  #pragma unroll
  for(int j=0;j<4;++j){ int i=base+j; v[j]=(i<N_NODES)?deg[i]:0; pre[j]=sum; sum+=v[j]; }
  s[t]=sum; __syncthreads();
  for(int off=1; off<256; off<<=1){
    int xv = (t>=off)? s[t-off]:0; __syncthreads();
    s[t]+=xv; __syncthreads();
  }
  int toff = (t>0)? s[t-1]:0;
  int g = part[blockIdx.x];
  #pragma unroll
  for(int j=0;j<4;++j){ int i=base+j; if(i<N_NODES) rowptr[i]=g+toff+pre[j]; }
}

// build CSR: src ids + edge_attr reordered (3 floats per edge)
__global__ void k_fill(const int* __restrict__ ei, const float* __restrict__ ea,
                       const int* __restrict__ rowptr, int* __restrict__ fill,
                       int* __restrict__ csr_src, float* __restrict__ ea_csr){
  int e = blockIdx.x*256+threadIdx.x;
  if(e>=N_EDGES) return;
  int dst = ei[N_EDGES+e];
  int pos = rowptr[dst] + atomicAdd(&fill[dst],1);
  csr_src[pos] = ei[e];
  ea_csr[(size_t)pos*3  ] = ea[e*3];
  ea_csr[(size_t)pos*3+1] = ea[e*3+1];
  ea_csr[(size_t)pos*3+2] = ea[e*3+2];
}

// xh = h16 @ gat_lin_w[l]  (A bf16, W split hi/lo -> 2 MFMAs) -> bf16-packed xhb
__global__ void k_gemm(const unsigned short* __restrict__ h16,
                       const unsigned short* __restrict__ whi,
                       const unsigned short* __restrict__ wlo,
                       const float* __restrict__ att_src_l, const float* __restrict__ att_dst_l,
                       unsigned* __restrict__ xhb, float* __restrict__ as_, float* __restrict__ ad_){
  int wave = threadIdx.x>>6, lane = threadIdx.x&63;
  int row0 = blockIdx.x*64 + wave*16;
  if(row0 >= N_NODES) return;
  int q = lane>>4, r = lane&15;
  const unsigned short* hrow = h16 + (size_t)(row0 + r)*HID;
  v8bf av[4];
  #pragma unroll
  for(int kb=0;kb<4;++kb)
    av[kb] = *(const v8bf*)(hrow + kb*32 + q*8);
  v4f acc[8];
  #pragma unroll
  for(int cg=0;cg<8;++cg){
    v4f a = {0.f,0.f,0.f,0.f};
    #pragma unroll
    for(int kb=0;kb<4;++kb){
      v8bf bhi = *(const v8bf*)(whi + ((kb*8+cg)*64 + lane)*8);
      v8bf blo = *(const v8bf*)(wlo + ((kb*8+cg)*64 + lane)*8);
      a = __builtin_amdgcn_mfma_f32_16x16x32_bf16(av[kb], blo, a, 0,0,0);
      a = __builtin_amdgcn_mfma_f32_16x16x32_bf16(av[kb], bhi, a, 0,0,0);
    }
    acc[cg]=a;
  }
  #pragma unroll
  for(int cg=0;cg<8;++cg){
    #pragma unroll
    for(int reg=0;reg<4;++reg){
      float v = acc[cg][reg];
      float o = __shfl_xor(v, 1);
      if((r&1)==0){
        unsigned pack = (unsigned)f2bf_bits(v) | ((unsigned)f2bf_bits(o)<<16);
        xhb[(size_t)(row0 + q*4 + reg)*64 + ((cg*16+r)>>1)] = pack;
      }
    }
  }
  #pragma unroll
  for(int hh=0; hh<4; ++hh){
    float sl = att_src_l[hh*32 + r],  sh2 = att_src_l[hh*32+16+r];
    float dl = att_dst_l[hh*32 + r],  dh  = att_dst_l[hh*32+16+r];
    #pragma unroll
    for(int reg=0;reg<4;++reg){
      float vs = acc[2*hh][reg]*sl + acc[2*hh+1][reg]*sh2;
      float vd = acc[2*hh][reg]*dl + acc[2*hh+1][reg]*dh;
      vs += __shfl_xor(vs,1); vs += __shfl_xor(vs,2); vs += __shfl_xor(vs,4); vs += __shfl_xor(vs,8);
      vd += __shfl_xor(vd,1); vd += __shfl_xor(vd,2); vd += __shfl_xor(vd,4); vd += __shfl_xor(vd,8);
      if(r==0){
        int rr = row0 + q*4 + reg;
        as_[rr*4+hh] = vs;
        ad_[rr*4+hh] = vd;
      }
    }
  }
}

// wave-per-node. Phase A: parallel softmax coefs; self-loop mean term reduced
// in-wave from the per-edge t_j = ea.Me terms (no eamean buffer). Phase B:
// half-wave uint2 gather. Epilogue: folded BN + relu + residual; writes fp32
// hbuf AND packed bf16 h16 (for next layer's GEMM).
__global__ void k_aggr(const unsigned* __restrict__ xhb, const float* __restrict__ as_,
    const float* __restrict__ ad_, const float* __restrict__ ea_csr,
    const float* __restrict__ mebuf,
    const int* __restrict__ rowptr, const int* __restrict__ csr_src,
    const float* __restrict__ bnA_l, const float* __restrict__ bnS_l,
    float* __restrict__ hbuf, unsigned* __restrict__ h16, int layer){
  __shared__ float lds_coef[4][MAXDEG*4];
  __shared__ int   lds_src[4][MAXDEG];
  __shared__ float sme[64];
  int w = threadIdx.x>>6, lane = threadIdx.x&63;
  if(threadIdx.x < 64) sme[threadIdx.x] = mebuf[threadIdx.x];
  __syncthreads();
  int node = blockIdx.x*4 + w;
  if(node >= N_NODES) return;
  int s = rowptr[node], e = rowptr[node+1];
  int deg = e - s;
  int l = lane&31, half = lane>>5, hh2 = l>>3;
  const uint2* xrow = (const uint2*)xhb;
  float a0,a1,a2,a3;

  if(deg <= MAXDEG){
    // ---- phase A ----
    int eidx = lane>>2, h = lane&3;
    int li = layer*4+h;
    float mec0=sme[li], mec1=sme[16+li], mec2=sme[32+li], meb=sme[48+li];
    float ad_h = ad_[node*4+h];
    int j0 = eidx, j1 = 16+eidx;
    float t0 = 0.f, t1 = 0.f;
    float g0 = -1e30f, g1 = -1e30f;
    int s0 = node, s1 = node;
    if(j0 < deg){
      s0 = csr_src[s+j0];
      float q0=ea_csr[(size_t)(s+j0)*3], q1=ea_csr[(size_t)(s+j0)*3+1], q2=ea_csr[(size_t)(s+j0)*3+2];
      t0 = q0*mec0+q1*mec1+q2*mec2;
      g0 = lrelu(as_[s0*4+h] + ad_h + t0 + meb);
    }
    if(j1 < deg){
      s1 = csr_src[s+j1];
      float q0=ea_csr[(size_t)(s+j1)*3], q1=ea_csr[(size_t)(s+j1)*3+1], q2=ea_csr[(size_t)(s+j1)*3+2];
      t1 = q0*mec0+q1*mec1+q2*mec2;
      g1 = lrelu(as_[s1*4+h] + ad_h + t1 + meb);
    }
    if(h==0){ lds_src[w][j0]=s0; lds_src[w][j1]=s1; }
    float ts = t0+t1;
    ts += __shfl_xor(ts,4); ts += __shfl_xor(ts,8);
    ts += __shfl_xor(ts,16); ts += __shfl_xor(ts,32);
    float lt = (deg>0) ? ts/(float)deg + meb : 0.f;
    float al = lrelu(as_[node*4+h] + ad_h + lt);
    float m = fmaxf(al, fmaxf(g0,g1));
    m = fmaxf(m, __shfl_xor(m,4)); m = fmaxf(m, __shfl_xor(m,8));
    m = fmaxf(m, __shfl_xor(m,16)); m = fmaxf(m, __shfl_xor(m,32));
    float e0 = (j0<deg)? __expf(g0-m) : 0.f;
    float e1 = (j1<deg)? __expf(g1-m) : 0.f;
    float ds = e0+e1;
    ds += __shfl_xor(ds,4); ds += __shfl_xor(ds,8);
    ds += __shfl_xor(ds,16); ds += __shfl_xor(ds,32);
    float es = __expf(al-m);
    float inv = 1.f/(ds+es);
    float cs = es*inv;
    lds_coef[w][j0*4+h] = e0*inv;
    lds_coef[w][j1*4+h] = e1*inv;
    // ---- phase B ----
    float cs4 = __shfl(cs, hh2);
    uint2 su = xrow[(size_t)node*32 + l];
    int pdeg = (deg+3)&~3;
    a0=a1=a2=a3=0.f;
    for(int j=0;j<pdeg;j+=4){
      float ca = lds_coef[w][(j+half)*4+hh2];
      float cb = lds_coef[w][(j+2+half)*4+hh2];
      int sa = lds_src[w][j+half], sb = lds_src[w][j+2+half];
      uint2 ua = xrow[(size_t)sa*32+l];
      uint2 ub = xrow[(size_t)sb*32+l];
      a0 += ca*bflo(ua.x) + cb*bflo(ub.x);
      a1 += ca*bfhi(ua.x) + cb*bfhi(ub.x);
      a2 += ca*bflo(ua.y) + cb*bflo(ub.y);
      a3 += ca*bfhi(ua.y) + cb*bfhi(ub.y);
    }
    a0 += __shfl_xor(a0,32); a1 += __shfl_xor(a1,32);
    a2 += __shfl_xor(a2,32); a3 += __shfl_xor(a3,32);
    a0 += cs4*bflo(su.x); a1 += cs4*bfhi(su.x);
    a2 += cs4*bflo(su.y); a3 += cs4*bfhi(su.y);
  } else {
    // fallback (deg > MAXDEG): serial online softmax, each lane 4 channels
    int li = layer*4+hh2;
    float mec0=sme[li], mec1=sme[16+li], mec2=sme[32+li], meb=sme[48+li];
    float adv = ad_[node*4+hh2];
    float ts = 0.f;
    for(int j=s;j<e;++j)
      ts += ea_csr[(size_t)j*3]*mec0 + ea_csr[(size_t)j*3+1]*mec1 + ea_csr[(size_t)j*3+2]*mec2;
    float al = lrelu(as_[node*4+hh2] + adv + ts/(float)deg + meb);
    float m = al, d = 1.f;
    uint2 su = xrow[(size_t)node*32 + l];
    float c0=bflo(su.x),c1=bfhi(su.x),c2=bflo(su.y),c3=bfhi(su.y);
    for(int j=s;j<e;++j){
      int sr = csr_src[j];
      float q0=ea_csr[(size_t)j*3], q1=ea_csr[(size_t)j*3+1], q2=ea_csr[(size_t)j*3+2];
      float b = lrelu(as_[sr*4+hh2] + adv + q0*mec0+q1*mec1+q2*mec2+meb);
      uint2 uv = xrow[(size_t)sr*32 + l];
      float nm = fmaxf(m,b);
      float sc = __expf(m-nm), eb = __expf(b-nm);
      d = d*sc + eb;
      c0 = c0*sc + eb*bflo(uv.x); c1 = c1*sc + eb*bfhi(uv.x);
      c2 = c2*sc + eb*bflo(uv.y); c3 = c3*sc + eb*bfhi(uv.y);
      m = nm;
    }
    float inv = 1.f/d;
    a0=c0*inv; a1=c1*inv; a2=c2*inv; a3=c3*inv;
  }

  if(half==0){
    const v4f* A4 = (const v4f*)bnA_l;
    const v4f* S4 = (const v4f*)bnS_l;
    v4f A = A4[l], S = S4[l];
    v4f* h4 = (v4f*)hbuf;
    v4f hres = h4[(size_t)node*32 + l];
    v4f o;
    o.x = fmaxf(a0*A.x+S.x, 0.f) + hres.x;
    o.y = fmaxf(a1*A.y+S.y, 0.f) + hres.y;
    o.z = fmaxf(a2*A.z+S.z, 0.f) + hres.z;
    o.w = fmaxf(a3*A.w+S.w, 0.f) + hres.w;
    h4[(size_t)node*32 + l] = o;
    uint2 p;
    p.x = (unsigned)f2bf_bits(o.x) | ((unsigned)f2bf_bits(o.y)<<16);
    p.y = (unsigned)f2bf_bits(o.z) | ((unsigned)f2bf_bits(o.w)<<16);
    ((uint2*)h16)[(size_t)node*32 + l] = p;
  }
}

__global__ void k_gptr(const int* __restrict__ batch, int* __restrict__ gptr){
  int g = blockIdx.x*256+threadIdx.x;
  if(g > N_GRAPHS) return;
  int lo=0, hi=N_NODES;
  while(lo<hi){ int mid=(lo+hi)>>1; if(batch[mid] < g) lo=mid+1; else hi=mid; }
  gptr[g]=lo;
}

__global__ void k_pool(const float* __restrict__ hbuf, const int* __restrict__ gptr,
                       float* __restrict__ gfeat){
  int g = blockIdx.x, c = threadIdx.x;
  int s = gptr[g], e = gptr[g+1];
  float sum=0.f, mx=-3.4e38f;
  for(int i=s;i<e;++i){ float v = hbuf[(size_t)i*HID+c]; sum+=v; mx=fmaxf(mx,v); }
  int cnt = e-s;
  float meanv = sum / (float)(cnt>1?cnt:1);
  if(cnt==0) mx=0.f;
  gfeat[g*384 + c] = meanv;
  gfeat[g*384 + 128 + c] = mx;
  gfeat[g*384 + 256 + c] = sum;
}

__global__ void k_head(const float* __restrict__ gfeat, const float* __restrict__ gf,
   const float* __restrict__ gc_w, const float* __restrict__ gc_b,
   const float* __restrict__ gf1_w, const float* __restrict__ gf1_b,
   const float* __restrict__ gf2_w, const float* __restrict__ gf2_b,
   const float* __restrict__ p1_w, const float* __restrict__ p1_b,
   const float* __restrict__ p2_w, const float* __restrict__ p2_b,
   const float* __restrict__ p3_w, const float* __restrict__ p3_b,
   float* __restrict__ out){
  __shared__ float sg[384];
  __shared__ float comb[192];
  __shared__ float hid1[64];
  __shared__ float r1[128];
  __shared__ float r2[64];
  int g = blockIdx.x, t = threadIdx.x;
  for(int i=t;i<384;i+=128) sg[i] = gfeat[g*384+i];
  if(t<64){
    float a = gf1_b[t];
    #pragma unroll
    for(int i=0;i<10;++i) a += gf[g*10+i]*gf1_w[i*64+t];
    hid1[t] = fmaxf(a,0.f);
  }
  __syncthreads();
  if(t<64){
    float a = gf2_b[t];
    for(int k=0;k<64;++k) a += hid1[k]*gf2_w[k*64+t];
    comb[128+t] = a;
  }
  {
    float a = gc_b[t];
    for(int k=0;k<384;++k) a += sg[k]*gc_w[k*128+t];
    comb[t] = fmaxf(a,0.f);
  }
  __syncthreads();
  {
    float a = p1_b[t];
    for(int k=0;k<192;++k) a += comb[k]*p1_w[k*128+t];
    r1[t] = fmaxf(a,0.f);
  }
  __syncthreads();
  if(t<64){
    float a = p2_b[t];
    for(int k=0;k<128;++k) a += r1[k]*p2_w[k*64+t];
    r2[t] = fmaxf(a,0.f);
  }
  __syncthreads();
  if(t<TOUT){
    float a = p3_b[t];
    for(int k=0;k<64;++k) a += r2[k]*p3_w[k*TOUT+t];
    out[g*TOUT+t] = a;
  }
}

extern "C" void kernel_launch(void* const* d_in, const int* in_sizes, int n_in,
                              void* d_out, int out_size, void* d_ws, size_t ws_size,
                              hipStream_t stream){
  (void)in_sizes; (void)n_in; (void)out_size; (void)ws_size;
  const float* x        = (const float*)d_in[0];
  const int*   ei       = (const int*)d_in[1];
  const float* ea       = (const float*)d_in[2];
  const int*   batch    = (const int*)d_in[3];
  const float* gfin     = (const float*)d_in[4];
  const float* node_w   = (const float*)d_in[5];
  const float* node_b   = (const float*)d_in[6];
  const float* edge_w   = (const float*)d_in[7];
  const float* edge_b   = (const float*)d_in[8];
  const float* gat_lin_w  = (const float*)d_in[9];
  const float* gat_edge_w = (const float*)d_in[10];
  const float* att_src  = (const float*)d_in[11];
  const float* att_dst  = (const float*)d_in[12];
  const float* att_edge = (const float*)d_in[13];
  const float* gat_bias = (const float*)d_in[14];
  const float* bn_gamma = (const float*)d_in[15];
  const float* bn_beta  = (const float*)d_in[16];
  const float* bn_mean  = (const float*)d_in[17];
  const float* bn_var   = (const float*)d_in[18];
  const float* gc_w = (const float*)d_in[19];
  const float* gc_b = (const float*)d_in[20];
  const float* gf1_w = (const float*)d_in[21];
  const float* gf1_b = (const float*)d_in[22];
  const float* gf2_w = (const float*)d_in[23];
  const float* gf2_b = (const float*)d_in[24];
  const float* p1_w = (const float*)d_in[25];
  const float* p1_b = (const float*)d_in[26];
  const float* p2_w = (const float*)d_in[27];
  const float* p2_b = (const float*)d_in[28];
  const float* p3_w = (const float*)d_in[29];
  const float* p3_b = (const float*)d_in[30];
  float* out = (float*)d_out;

  char* w = (char*)d_ws;
  size_t o = 0;
  auto carve = [&](size_t bytes)->char*{
    char* p = w + o; o += (bytes + 255) & ~(size_t)255; return p;
  };
  unsigned* xhb = (unsigned*)carve((size_t)N_NODES*64*4);
  float* hbuf   = (float*)carve((size_t)N_NODES*HID*4);
  unsigned* h16 = (unsigned*)carve((size_t)N_NODES*64*4);
  float* ea_csr = (float*)carve((size_t)N_EDGES*3*4);
  float* as_    = (float*)carve((size_t)N_NODES*4*4);
  float* ad_    = (float*)carve((size_t)N_NODES*4*4);
  int* deg      = (int*)carve((size_t)N_NODES*4);
  int* rowptr   = (int*)carve((size_t)(N_NODES+1)*4);
  int* fill     = (int*)carve((size_t)N_NODES*4);
  int* csr_src  = (int*)carve((size_t)N_EDGES*4);
  int* part     = (int*)carve(1024*4);
  float* mebuf  = (float*)carve(64*4);
  float* bnA    = (float*)carve((size_t)NLAYER*HID*4);
  float* bnS    = (float*)carve((size_t)NLAYER*HID*4);
  unsigned short* whi = (unsigned short*)carve(65536*2);
  unsigned short* wlo = (unsigned short*)carve(65536*2);
  int* gptr     = (int*)carve((size_t)(N_GRAPHS+1)*4);
  float* gfeat  = (float*)carve((size_t)N_GRAPHS*384*4);

  (void)hipMemsetAsync(deg, 0, (size_t)N_NODES*4, stream);
  (void)hipMemsetAsync(fill, 0, (size_t)N_NODES*4, stream);

  k_prep<<<1,256,0,stream>>>(gat_edge_w, att_edge, edge_w, edge_b,
        gat_bias, bn_gamma, bn_beta, bn_mean, bn_var, mebuf, bnA, bnS);
  k_wswz<<<256,256,0,stream>>>(gat_lin_w, whi, wlo);
  k_hinit<<<N_NODES/2,256,0,stream>>>(x, node_w, node_b, hbuf, h16);
  k_deg<<<(N_EDGES+255)/256,256,0,stream>>>(ei, deg);
  int nb = (N_NODES+1023)/1024;
  k_scan1<<<nb,256,0,stream>>>(deg, part);
  k_scan2<<<1,64,0,stream>>>(part, rowptr, nb);
  k_scan3<<<nb,256,0,stream>>>(deg, part, rowptr);
  k_fill<<<(N_EDGES+255)/256,256,0,stream>>>(ei, ea, rowptr, fill, csr_src, ea_csr);

  for(int l=0;l<NLAYER;++l){
    k_gemm<<<(N_NODES+63)/64,256,0,stream>>>((const unsigned short*)h16,
        whi + l*16384, wlo + l*16384,
        att_src + l*128, att_dst + l*128, xhb, as_, ad_);
    k_aggr<<<(N_NODES+3)/4,256,0,stream>>>(xhb, as_, ad_, ea_csr, mebuf,
        rowptr, csr_src, bnA + l*128, bnS + l*128, hbuf, h16, l);
  }

  k_gptr<<<(N_GRAPHS+256)/256,256,0,stream>>>(batch, gptr);
  k_pool<<<N_GRAPHS,128,0,stream>>>(hbuf, gptr, gfeat);
  k_head<<<N_GRAPHS,128,0,stream>>>(gfeat, gfin, gc_w, gc_b, gf1_w, gf1_b, gf2_w, gf2_b,
        p1_w, p1_b, p2_w, p2_b, p3_w, p3_b, out);
}

// Round 9
// 605.947 us; speedup vs baseline: 1.0552x; 1.0552x over previous
//
#include <hip/hip_runtime.h>

#define N_NODES 100000
#define N_EDGES 400000
#define N_GRAPHS 2048
#define HID 128
#define NLAYER 4
#define TOUT 5
#define EPSV 1e-5f
#define SLOPE 0.2f
#define MAXDEG 32

typedef float v4f __attribute__((ext_vector_type(4)));
typedef __bf16 v8bf __attribute__((ext_vector_type(8)));

static __device__ __forceinline__ unsigned short f2bf_bits(float f){
  unsigned u = __builtin_bit_cast(unsigned, f);
  unsigned r = u + 0x7fffu + ((u >> 16) & 1u);
  return (unsigned short)(r >> 16);
}
static __device__ __forceinline__ float bfbits2f(unsigned short s){
  unsigned u = ((unsigned)s) << 16;
  return __builtin_bit_cast(float, u);
}
static __device__ __forceinline__ float bflo(unsigned u){
  return __builtin_bit_cast(float, u << 16);
}
static __device__ __forceinline__ float bfhi(unsigned u){
  return __builtin_bit_cast(float, u & 0xffff0000u);
}
static __device__ __forceinline__ float lrelu(float v){
  return v>0.f ? v : SLOPE*v;
}

// h = x @ node_w + node_b  -> packed bf16 h16 only
__global__ void k_hinit(const float* __restrict__ x, const float* __restrict__ nw,
                        const float* __restrict__ nb, unsigned* __restrict__ h16){
  int t = threadIdx.x;
  int node = blockIdx.x*2 + (t>>7);
  int c = t&127;
  float acc = nb[c];
  #pragma unroll
  for(int f=0; f<7; ++f) acc += x[node*7+f]*nw[f*HID+c];
  float o = __shfl_xor(acc,1);
  if((c&1)==0){
    unsigned p = (unsigned)f2bf_bits(acc) | ((unsigned)f2bf_bits(o)<<16);
    h16[((size_t)node*HID+c)>>1] = p;
  }
}

// prep Me[3][16]+be[16]  AND folded BN (A,S)
__global__ void k_prep(const float* __restrict__ gat_edge_w, const float* __restrict__ att_edge,
                       const float* __restrict__ edge_w, const float* __restrict__ edge_b,
                       const float* __restrict__ gat_bias, const float* __restrict__ gamma,
                       const float* __restrict__ beta, const float* __restrict__ mean,
                       const float* __restrict__ var,
                       float* __restrict__ mebuf, float* __restrict__ bnA, float* __restrict__ bnS){
  __shared__ float Ve[128*16];
  int t = threadIdx.x;
  for(int i=t; i<NLAYER*HID; i+=256){
    float A = gamma[i]*rsqrtf(var[i]+EPSV);
    bnA[i] = A;
    bnS[i] = (gat_bias[i]-mean[i])*A + beta[i];
  }
  for(int id=t; id<2048; id+=256){
    int k = id>>4, li = id&15, l = li>>2, hh = li&3;
    const float* gw = gat_edge_w + l*16384 + k*128 + hh*32;
    const float* at = att_edge + l*128 + hh*32;
    float s = 0.f;
    #pragma unroll
    for(int c=0;c<32;++c) s += gw[c]*at[c];
    Ve[k*16+li] = s;
  }
  __syncthreads();
  if(t < 48){
    int f = t>>4, li = t&15;
    float s=0.f;
    for(int k=0;k<128;++k) s += edge_w[f*128+k]*Ve[k*16+li];
    mebuf[f*16+li] = s;
  } else if (t < 64){
    int li = t-48; float s=0.f;
    for(int k=0;k<128;++k) s += edge_b[k]*Ve[k*16+li];
    mebuf[48+li] = s;
  }
}

// swizzle gat_lin_w into MFMA B-fragment order, split into bf16 hi/lo
__global__ void k_wswz(const float* __restrict__ W, unsigned short* __restrict__ whi,
                       unsigned short* __restrict__ wlo){
  int idx = blockIdx.x*256 + threadIdx.x; // l*16384 + k*128 + c
  int l = idx>>14, k = (idx>>7)&127, c = idx&127;
  float w = W[idx];
  unsigned short hi = f2bf_bits(w);
  unsigned short lo = f2bf_bits(w - bfbits2f(hi));
  int kb=k>>5, quad=(k>>3)&3, j=k&7, cg=c>>4, r=c&15, lane=quad*16+r;
  int dst = ((l*4+kb)*8+cg)*512 + lane*8 + j;
  whi[dst]=hi; wlo[dst]=lo;
}

__global__ void k_deg(const int* __restrict__ ei, int* __restrict__ deg){
  int e = blockIdx.x*256 + threadIdx.x;
  if(e >= N_EDGES) return;
  atomicAdd(&deg[ei[N_EDGES+e]], 1);
}

// exclusive scan of deg -> rowptr (3 phases, chunk=1024)
__global__ void k_scan1(const int* __restrict__ deg, int* __restrict__ part){
  __shared__ int s[256];
  int t=threadIdx.x; int base = blockIdx.x*1024 + t*4;
  int sum=0;
  #pragma unroll
  for(int j=0;j<4;++j){ int i=base+j; sum += (i<N_NODES)? deg[i]:0; }
  s[t]=sum; __syncthreads();
  for(int off=128; off>0; off>>=1){ if(t<off) s[t]+=s[t+off]; __syncthreads(); }
  if(t==0) part[blockIdx.x]=s[0];
}
__global__ void k_scan2(int* __restrict__ part, int* __restrict__ rowptr, int nb){
  if(threadIdx.x==0 && blockIdx.x==0){
    int run=0;
    for(int i=0;i<nb;++i){ int v=part[i]; part[i]=run; run+=v; }
    rowptr[N_NODES]=run;
  }
}
__global__ void k_scan3(const int* __restrict__ deg, const int* __restrict__ part, int* __restrict__ rowptr){
  __shared__ int s[256];
  int t=threadIdx.x; int base = blockIdx.x*1024 + t*4;
  int v[4]; int sum=0; int pre[4];
  #pragma unroll
  for(int j=0;j<4;++j){ int i=base+j; v[j]=(i<N_NODES)?deg[i]:0; pre[j]=sum; sum+=v[j]; }
  s[t]=sum; __syncthreads();
  for(int off=1; off<256; off<<=1){
    int xv = (t>=off)? s[t-off]:0; __syncthreads();
    s[t]+=xv; __syncthreads();
  }
  int toff = (t>0)? s[t-1]:0;
  int g = part[blockIdx.x];
  #pragma unroll
  for(int j=0;j<4;++j){ int i=base+j; if(i<N_NODES) rowptr[i]=g+toff+pre[j]; }
}

// build CSR: src ids + edge_attr reordered (3 floats per edge)
__global__ void k_fill(const int* __restrict__ ei, const float* __restrict__ ea,
                       const int* __restrict__ rowptr, int* __restrict__ fill,
                       int* __restrict__ csr_src, float* __restrict__ ea_csr){
  int e = blockIdx.x*256+threadIdx.x;
  if(e>=N_EDGES) return;
  int dst = ei[N_EDGES+e];
  int pos = rowptr[dst] + atomicAdd(&fill[dst],1);
  csr_src[pos] = ei[e];
  ea_csr[(size_t)pos*3  ] = ea[e*3];
  ea_csr[(size_t)pos*3+1] = ea[e*3+1];
  ea_csr[(size_t)pos*3+2] = ea[e*3+2];
}

// xh = h16 @ gat_lin_w[l]  (A bf16, W split hi/lo -> 2 MFMAs) -> bf16-packed xhb
__global__ void k_gemm(const unsigned short* __restrict__ h16,
                       const unsigned short* __restrict__ whi,
                       const unsigned short* __restrict__ wlo,
                       const float* __restrict__ att_src_l, const float* __restrict__ att_dst_l,
                       unsigned* __restrict__ xhb, float* __restrict__ as_, float* __restrict__ ad_){
  int wave = threadIdx.x>>6, lane = threadIdx.x&63;
  int row0 = blockIdx.x*64 + wave*16;
  if(row0 >= N_NODES) return;
  int q = lane>>4, r = lane&15;
  const unsigned short* hrow = h16 + (size_t)(row0 + r)*HID;
  v8bf av[4];
  #pragma unroll
  for(int kb=0;kb<4;++kb)
    av[kb] = *(const v8bf*)(hrow + kb*32 + q*8);
  v4f acc[8];
  #pragma unroll
  for(int cg=0;cg<8;++cg){
    v4f a = {0.f,0.f,0.f,0.f};
    #pragma unroll
    for(int kb=0;kb<4;++kb){
      v8bf bhi = *(const v8bf*)(whi + ((kb*8+cg)*64 + lane)*8);
      v8bf blo = *(const v8bf*)(wlo + ((kb*8+cg)*64 + lane)*8);
      a = __builtin_amdgcn_mfma_f32_16x16x32_bf16(av[kb], blo, a, 0,0,0);
      a = __builtin_amdgcn_mfma_f32_16x16x32_bf16(av[kb], bhi, a, 0,0,0);
    }
    acc[cg]=a;
  }
  #pragma unroll
  for(int cg=0;cg<8;++cg){
    #pragma unroll
    for(int reg=0;reg<4;++reg){
      float v = acc[cg][reg];
      float o = __shfl_xor(v, 1);
      if((r&1)==0){
        unsigned pack = (unsigned)f2bf_bits(v) | ((unsigned)f2bf_bits(o)<<16);
        xhb[(size_t)(row0 + q*4 + reg)*64 + ((cg*16+r)>>1)] = pack;
      }
    }
  }
  #pragma unroll
  for(int hh=0; hh<4; ++hh){
    float sl = att_src_l[hh*32 + r],  sh2 = att_src_l[hh*32+16+r];
    float dl = att_dst_l[hh*32 + r],  dh  = att_dst_l[hh*32+16+r];
    #pragma unroll
    for(int reg=0;reg<4;++reg){
      float vs = acc[2*hh][reg]*sl + acc[2*hh+1][reg]*sh2;
      float vd = acc[2*hh][reg]*dl + acc[2*hh+1][reg]*dh;
      vs += __shfl_xor(vs,1); vs += __shfl_xor(vs,2); vs += __shfl_xor(vs,4); vs += __shfl_xor(vs,8);
      vd += __shfl_xor(vd,1); vd += __shfl_xor(vd,2); vd += __shfl_xor(vd,4); vd += __shfl_xor(vd,8);
      if(r==0){
        int rr = row0 + q*4 + reg;
        as_[rr*4+hh] = vs;
        ad_[rr*4+hh] = vd;
      }
    }
  }
}

// wave-per-node, waves fully independent (no block-level sync).
// Phase A: parallel softmax coefs; mebuf read through L1 (no LDS staging).
// Phase B: half-wave uint2 gather. Epilogue: folded BN + relu + residual
// (residual from h16 bf16); writes h16 (layers 0..L-2) or fp32 hbuf (last).
__global__ void k_aggr(const unsigned* __restrict__ xhb, const float* __restrict__ as_,
    const float* __restrict__ ad_, const float* __restrict__ ea_csr,
    const float* __restrict__ mebuf,
    const int* __restrict__ rowptr, const int* __restrict__ csr_src,
    const float* __restrict__ bnA_l, const float* __restrict__ bnS_l,
    unsigned* __restrict__ h16, float* __restrict__ hbuf, int layer, int last){
  __shared__ float lds_coef[4][MAXDEG*4];
  __shared__ int   lds_src[4][MAXDEG];
  int w = threadIdx.x>>6, lane = threadIdx.x&63;
  int node = blockIdx.x*4 + w;
  if(node >= N_NODES) return;
  int s = rowptr[node], e = rowptr[node+1];
  int deg = e - s;
  int l = lane&31, half = lane>>5, hh2 = l>>3;
  const uint2* xrow = (const uint2*)xhb;
  float a0,a1,a2,a3;

  if(deg <= MAXDEG){
    // ---- phase A ----
    int eidx = lane>>2, h = lane&3;
    int li = layer*4+h;
    float mec0=mebuf[li], mec1=mebuf[16+li], mec2=mebuf[32+li], meb=mebuf[48+li];
    float ad_h = ad_[node*4+h];
    int j0 = eidx, j1 = 16+eidx;
    float t0 = 0.f, t1 = 0.f;
    float g0 = -1e30f, g1 = -1e30f;
    int s0 = node, s1 = node;
    if(j0 < deg){
      s0 = csr_src[s+j0];
      float q0=ea_csr[(size_t)(s+j0)*3], q1=ea_csr[(size_t)(s+j0)*3+1], q2=ea_csr[(size_t)(s+j0)*3+2];
      t0 = q0*mec0+q1*mec1+q2*mec2;
      g0 = lrelu(as_[s0*4+h] + ad_h + t0 + meb);
    }
    if(j1 < deg){
      s1 = csr_src[s+j1];
      float q0=ea_csr[(size_t)(s+j1)*3], q1=ea_csr[(size_t)(s+j1)*3+1], q2=ea_csr[(size_t)(s+j1)*3+2];
      t1 = q0*mec0+q1*mec1+q2*mec2;
      g1 = lrelu(as_[s1*4+h] + ad_h + t1 + meb);
    }
    if(h==0){ lds_src[w][j0]=s0; lds_src[w][j1]=s1; }
    float ts = t0+t1;
    ts += __shfl_xor(ts,4); ts += __shfl_xor(ts,8);
    ts += __shfl_xor(ts,16); ts += __shfl_xor(ts,32);
    float lt = (deg>0) ? ts/(float)deg + meb : 0.f;
    float al = lrelu(as_[node*4+h] + ad_h + lt);
    float m = fmaxf(al, fmaxf(g0,g1));
    m = fmaxf(m, __shfl_xor(m,4)); m = fmaxf(m, __shfl_xor(m,8));
    m = fmaxf(m, __shfl_xor(m,16)); m = fmaxf(m, __shfl_xor(m,32));
    float e0 = (j0<deg)? __expf(g0-m) : 0.f;
    float e1 = (j1<deg)? __expf(g1-m) : 0.f;
    float ds = e0+e1;
    ds += __shfl_xor(ds,4); ds += __shfl_xor(ds,8);
    ds += __shfl_xor(ds,16); ds += __shfl_xor(ds,32);
    float es = __expf(al-m);
    float inv = 1.f/(ds+es);
    float cs = es*inv;
    lds_coef[w][j0*4+h] = e0*inv;
    lds_coef[w][j1*4+h] = e1*inv;
    // ---- phase B ----
    float cs4 = __shfl(cs, hh2);
    uint2 su = xrow[(size_t)node*32 + l];
    int pdeg = (deg+3)&~3;
    a0=a1=a2=a3=0.f;
    for(int j=0;j<pdeg;j+=4){
      float ca = lds_coef[w][(j+half)*4+hh2];
      float cb = lds_coef[w][(j+2+half)*4+hh2];
      int sa = lds_src[w][j+half], sb = lds_src[w][j+2+half];
      uint2 ua = xrow[(size_t)sa*32+l];
      uint2 ub = xrow[(size_t)sb*32+l];
      a0 += ca*bflo(ua.x) + cb*bflo(ub.x);
      a1 += ca*bfhi(ua.x) + cb*bfhi(ub.x);
      a2 += ca*bflo(ua.y) + cb*bflo(ub.y);
      a3 += ca*bfhi(ua.y) + cb*bfhi(ub.y);
    }
    a0 += __shfl_xor(a0,32); a1 += __shfl_xor(a1,32);
    a2 += __shfl_xor(a2,32); a3 += __shfl_xor(a3,32);
    a0 += cs4*bflo(su.x); a1 += cs4*bfhi(su.x);
    a2 += cs4*bflo(su.y); a3 += cs4*bfhi(su.y);
  } else {
    // fallback (deg > MAXDEG): serial online softmax, each lane 4 channels
    int li = layer*4+hh2;
    float mec0=mebuf[li], mec1=mebuf[16+li], mec2=mebuf[32+li], meb=mebuf[48+li];
    float adv = ad_[node*4+hh2];
    float ts = 0.f;
    for(int j=s;j<e;++j)
      ts += ea_csr[(size_t)j*3]*mec0 + ea_csr[(size_t)j*3+1]*mec1 + ea_csr[(size_t)j*3+2]*mec2;
    float al = lrelu(as_[node*4+hh2] + adv + ts/(float)deg + meb);
    float m = al, d = 1.f;
    uint2 su = xrow[(size_t)node*32 + l];
    float c0=bflo(su.x),c1=bfhi(su.x),c2=bflo(su.y),c3=bfhi(su.y);
    for(int j=s;j<e;++j){
      int sr = csr_src[j];
      float q0=ea_csr[(size_t)j*3], q1=ea_csr[(size_t)j*3+1], q2=ea_csr[(size_t)j*3+2];
      float b = lrelu(as_[sr*4+hh2] + adv + q0*mec0+q1*mec1+q2*mec2+meb);
      uint2 uv = xrow[(size_t)sr*32 + l];
      float nm = fmaxf(m,b);
      float sc = __expf(m-nm), eb = __expf(b-nm);
      d = d*sc + eb;
      c0 = c0*sc + eb*bflo(uv.x); c1 = c1*sc + eb*bfhi(uv.x);
      c2 = c2*sc + eb*bflo(uv.y); c3 = c3*sc + eb*bfhi(uv.y);
      m = nm;
    }
    float inv = 1.f/d;
    a0=c0*inv; a1=c1*inv; a2=c2*inv; a3=c3*inv;
  }

  if(half==0){
    const v4f* A4 = (const v4f*)bnA_l;
    const v4f* S4 = (const v4f*)bnS_l;
    v4f A = A4[l], S = S4[l];
    uint2 hr = ((const uint2*)h16)[(size_t)node*32 + l];
    float o0 = fmaxf(a0*A.x+S.x, 0.f) + bflo(hr.x);
    float o1 = fmaxf(a1*A.y+S.y, 0.f) + bfhi(hr.x);
    float o2 = fmaxf(a2*A.z+S.z, 0.f) + bflo(hr.y);
    float o3 = fmaxf(a3*A.w+S.w, 0.f) + bfhi(hr.y);
    if(last){
      v4f o = {o0,o1,o2,o3};
      ((v4f*)hbuf)[(size_t)node*32 + l] = o;
    } else {
      uint2 p;
      p.x = (unsigned)f2bf_bits(o0) | ((unsigned)f2bf_bits(o1)<<16);
      p.y = (unsigned)f2bf_bits(o2) | ((unsigned)f2bf_bits(o3)<<16);
      ((uint2*)h16)[(size_t)node*32 + l] = p;
    }
  }
}

// pool with fused graph-boundary binary search
__global__ void k_pool(const float* __restrict__ hbuf, const int* __restrict__ batch,
                       float* __restrict__ gfeat){
  __shared__ int sb[2];
  int g = blockIdx.x, c = threadIdx.x;
  if(c < 2){
    int target = g + c;
    int lo=0, hi=N_NODES;
    while(lo<hi){ int mid=(lo+hi)>>1; if(batch[mid] < target) lo=mid+1; else hi=mid; }
    sb[c]=lo;
  }
  __syncthreads();
  int s = sb[0], e = sb[1];
  float sum=0.f, mx=-3.4e38f;
  for(int i=s;i<e;++i){ float v = hbuf[(size_t)i*HID+c]; sum+=v; mx=fmaxf(mx,v); }
  int cnt = e-s;
  float meanv = sum / (float)(cnt>1?cnt:1);
  if(cnt==0) mx=0.f;
  gfeat[g*384 + c] = meanv;
  gfeat[g*384 + 128 + c] = mx;
  gfeat[g*384 + 256 + c] = sum;
}

__global__ void k_head(const float* __restrict__ gfeat, const float* __restrict__ gf,
   const float* __restrict__ gc_w, const float* __restrict__ gc_b,
   const float* __restrict__ gf1_w, const float* __restrict__ gf1_b,
   const float* __restrict__ gf2_w, const float* __restrict__ gf2_b,
   const float* __restrict__ p1_w, const float* __restrict__ p1_b,
   const float* __restrict__ p2_w, const float* __restrict__ p2_b,
   const float* __restrict__ p3_w, const float* __restrict__ p3_b,
   float* __restrict__ out){
  __shared__ float sg[384];
  __shared__ float comb[192];
  __shared__ float hid1[64];
  __shared__ float r1[128];
  __shared__ float r2[64];
  int g = blockIdx.x, t = threadIdx.x;
  for(int i=t;i<384;i+=128) sg[i] = gfeat[g*384+i];
  if(t<64){
    float a = gf1_b[t];
    #pragma unroll
    for(int i=0;i<10;++i) a += gf[g*10+i]*gf1_w[i*64+t];
    hid1[t] = fmaxf(a,0.f);
  }
  __syncthreads();
  if(t<64){
    float a = gf2_b[t];
    for(int k=0;k<64;++k) a += hid1[k]*gf2_w[k*64+t];
    comb[128+t] = a;
  }
  {
    float a = gc_b[t];
    for(int k=0;k<384;++k) a += sg[k]*gc_w[k*128+t];
    comb[t] = fmaxf(a,0.f);
  }
  __syncthreads();
  {
    float a = p1_b[t];
    for(int k=0;k<192;++k) a += comb[k]*p1_w[k*128+t];
    r1[t] = fmaxf(a,0.f);
  }
  __syncthreads();
  if(t<64){
    float a = p2_b[t];
    for(int k=0;k<128;++k) a += r1[k]*p2_w[k*64+t];
    r2[t] = fmaxf(a,0.f);
  }
  __syncthreads();
  if(t<TOUT){
    float a = p3_b[t];
    for(int k=0;k<64;++k) a += r2[k]*p3_w[k*TOUT+t];
    out[g*TOUT+t] = a;
  }
}

extern "C" void kernel_launch(void* const* d_in, const int* in_sizes, int n_in,
                              void* d_out, int out_size, void* d_ws, size_t ws_size,
                              hipStream_t stream){
  (void)in_sizes; (void)n_in; (void)out_size; (void)ws_size;
  const float* x        = (const float*)d_in[0];
  const int*   ei       = (const int*)d_in[1];
  const float* ea       = (const float*)d_in[2];
  const int*   batch    = (const int*)d_in[3];
  const float* gfin     = (const float*)d_in[4];
  const float* node_w   = (const float*)d_in[5];
  const float* node_b   = (const float*)d_in[6];
  const float* edge_w   = (const float*)d_in[7];
  const float* edge_b   = (const float*)d_in[8];
  const float* gat_lin_w  = (const float*)d_in[9];
  const float* gat_edge_w = (const float*)d_in[10];
  const float* att_src  = (const float*)d_in[11];
  const float* att_dst  = (const float*)d_in[12];
  const float* att_edge = (const float*)d_in[13];
  const float* gat_bias = (const float*)d_in[14];
  const float* bn_gamma = (const float*)d_in[15];
  const float* bn_beta  = (const float*)d_in[16];
  const float* bn_mean  = (const float*)d_in[17];
  const float* bn_var   = (const float*)d_in[18];
  const float* gc_w = (const float*)d_in[19];
  const float* gc_b = (const float*)d_in[20];
  const float* gf1_w = (const float*)d_in[21];
  const float* gf1_b = (const float*)d_in[22];
  const float* gf2_w = (const float*)d_in[23];
  const float* gf2_b = (const float*)d_in[24];
  const float* p1_w = (const float*)d_in[25];
  const float* p1_b = (const float*)d_in[26];
  const float* p2_w = (const float*)d_in[27];
  const float* p2_b = (const float*)d_in[28];
  const float* p3_w = (const float*)d_in[29];
  const float* p3_b = (const float*)d_in[30];
  float* out = (float*)d_out;

  char* w = (char*)d_ws;
  size_t o = 0;
  auto carve = [&](size_t bytes)->char*{
    char* p = w + o; o += (bytes + 255) & ~(size_t)255; return p;
  };
  unsigned* xhb = (unsigned*)carve((size_t)N_NODES*64*4);
  float* hbuf   = (float*)carve((size_t)N_NODES*HID*4);
  unsigned* h16 = (unsigned*)carve((size_t)N_NODES*64*4);
  float* ea_csr = (float*)carve((size_t)N_EDGES*3*4);
  float* as_    = (float*)carve((size_t)N_NODES*4*4);
  float* ad_    = (float*)carve((size_t)N_NODES*4*4);
  int* deg      = (int*)carve((size_t)N_NODES*4);
  int* rowptr   = (int*)carve((size_t)(N_NODES+1)*4);
  int* fill     = (int*)carve((size_t)N_NODES*4);
  int* csr_src  = (int*)carve((size_t)N_EDGES*4);
  int* part     = (int*)carve(1024*4);
  float* mebuf  = (float*)carve(64*4);
  float* bnA    = (float*)carve((size_t)NLAYER*HID*4);
  float* bnS    = (float*)carve((size_t)NLAYER*HID*4);
  unsigned short* whi = (unsigned short*)carve(65536*2);
  unsigned short* wlo = (unsigned short*)carve(65536*2);
  float* gfeat  = (float*)carve((size_t)N_GRAPHS*384*4);

  (void)hipMemsetAsync(deg, 0, (size_t)N_NODES*4, stream);
  (void)hipMemsetAsync(fill, 0, (size_t)N_NODES*4, stream);

  k_prep<<<1,256,0,stream>>>(gat_edge_w, att_edge, edge_w, edge_b,
        gat_bias, bn_gamma, bn_beta, bn_mean, bn_var, mebuf, bnA, bnS);
  k_wswz<<<256,256,0,stream>>>(gat_lin_w, whi, wlo);
  k_hinit<<<N_NODES/2,256,0,stream>>>(x, node_w, node_b, h16);
  k_deg<<<(N_EDGES+255)/256,256,0,stream>>>(ei, deg);
  int nb = (N_NODES+1023)/1024;
  k_scan1<<<nb,256,0,stream>>>(deg, part);
  k_scan2<<<1,64,0,stream>>>(part, rowptr, nb);
  k_scan3<<<nb,256,0,stream>>>(deg, part, rowptr);
  k_fill<<<(N_EDGES+255)/256,256,0,stream>>>(ei, ea, rowptr, fill, csr_src, ea_csr);

  for(int l=0;l<NLAYER;++l){
    k_gemm<<<(N_NODES+63)/64,256,0,stream>>>((const unsigned short*)h16,
        whi + l*16384, wlo + l*16384,
        att_src + l*128, att_dst + l*128, xhb, as_, ad_);
    k_aggr<<<(N_NODES+3)/4,256,0,stream>>>(xhb, as_, ad_, ea_csr, mebuf,
        rowptr, csr_src, bnA + l*128, bnS + l*128, h16, hbuf, l, (l==NLAYER-1)?1:0);
  }

  k_pool<<<N_GRAPHS,128,0,stream>>>(hbuf, batch, gfeat);
  k_head<<<N_GRAPHS,128,0,stream>>>(gfeat, gfin, gc_w, gc_b, gf1_w, gf1_b, gf2_w, gf2_b,
        p1_w, p1_b, p2_w, p2_b, p3_w, p3_b, out);
}